// Round 13
// baseline (5043.412 us; speedup 1.0000x reference)
//
#include <hip/hip_runtime.h>
#include <hip/hip_bf16.h>

// RNN: outs[t] = h_t = tanh(x[t]@Wx + b + h_{t-1}@Wh), T=512,B=64,IN=512,H=1024
//  - split-bf16 (hi+lo) MFMA everywhere (no fp32 MFMA on CDNA4); 3-term product
//  - phase A: xw = x@Wx+b written directly into d_out (overwritten by h_t in place)
//  - scan: persistent wgs, Wh register-resident, self-validating tagged-f32 h
//    (low 7 mantissa bits = epoch tag 64|(t&63); the poll IS the data load).
//  - R1 coherent-h only: 15.5->9.5 us/step. R2 flag barrier: REGRESSED.
//  - R3 self-validating h: ->6.4. R4 XCD-local: DEADLOCK (polled bytes must use
//    architecturally-coherent ops). R5 swap-RMW+chunk retries: ->5.9.
//  - R6 group-packed col-major layout + LDS bounce: ->4.6.
//  - R7 compute inside poll loop: REGRESSED -> polls must stay tight.
//  - R8 shared LDS h-image, 512-thr wgs: ->4.16.  R9 8-row groups + early-
//    issued sweep: ->3.66.
//  - R10 courier/compute split: correctness bug (unguarded compCnt).
//  - R11 fixed: REGRESSED (5.07) -> courier indirection adds a serial hop and
//    bounces inside the courier poll delay re-polls. Consumers must poll their
//    own data; hand-offs must be off the detect path.
//  - R12: R9 + poll-slice remap (wave (ks,ch) polls slice 2ks+ch, inside its
//    own compute range) + per-slice LDS flags replacing barrier1 + OWN-half
//    MFMA immediately after own bounce, partner-half after partner's flag.
//    One __syncthreads/step (barrier2); hx+partial parity double-buffered.

#define T_ 512
#define B_ 64
#define IN_ 512
#define H_ 1024
constexpr int TBH = T_ * B_ * H_;   // 33,554,432
constexpr int HB  = B_ * H_;        // 65,536
constexpr int GP8 = 1024 * 8;       // u32s per (group,parity) packed slice (8 rows)

typedef unsigned short u16;
typedef unsigned int u32;
typedef unsigned long long u64;
typedef __attribute__((ext_vector_type(8))) short short8;   // 8 x bf16 (4 VGPRs)
typedef __attribute__((ext_vector_type(4))) float f32x4;

__device__ __forceinline__ void splitbf(float x, u16& hi, u16& lo) {
    unsigned u = __float_as_uint(x);
    hi = (u16)(u >> 16);                       // truncated bf16 hi
    float r = x - __uint_as_float(u & 0xffff0000u);
    lo = (u16)(__float_as_uint(r) >> 16);      // bf16 of residual; total rel err ~2^-16
}

// ---- prep kernels ------------------------------------------------------------
__global__ void k_split4(const float4* __restrict__ in, u16* __restrict__ hi,
                         u16* __restrict__ lo, int n4) {
    int i = blockIdx.x * blockDim.x + threadIdx.x;
    int stride = gridDim.x * blockDim.x;
    for (; i < n4; i += stride) {
        float4 v = in[i];
        u16 h0,h1,h2,h3,l0,l1,l2,l3;
        splitbf(v.x,h0,l0); splitbf(v.y,h1,l1); splitbf(v.z,h2,l2); splitbf(v.w,h3,l3);
        uint2 hv, lv;
        hv.x = (unsigned)h0 | ((unsigned)h1 << 16);
        hv.y = (unsigned)h2 | ((unsigned)h3 << 16);
        lv.x = (unsigned)l0 | ((unsigned)l1 << 16);
        lv.y = (unsigned)l2 | ((unsigned)l3 << 16);
        *(uint2*)&hi[4*i] = hv;
        *(uint2*)&lo[4*i] = lv;
    }
}

// src [K][N] fp32 -> dst [N][K] bf16 hi/lo (transposed for B-fragment reads)
__global__ void k_tsplit(const float* __restrict__ src, u16* __restrict__ hi,
                         u16* __restrict__ lo, int K, int N) {
    int id = blockIdx.x * 256 + threadIdx.x;
    if (id >= K * N) return;
    int k = id / N, n = id % N;
    u16 h, l; splitbf(src[id], h, l);
    hi[n*K + k] = h; lo[n*K + k] = l;
}

// h0 fp32 [B][H] -> packed tagged-f32 parity-1 (read at t=0, expects tag 127)
__global__ void k_h0(const float* __restrict__ h0, u32* __restrict__ hbufP) {
    int id = blockIdx.x * 256 + threadIdx.x;
    if (id >= HB) return;
    int b = id >> 10, k = id & 1023;
    u32 u = __float_as_uint(h0[id]);
    hbufP[(size_t)((b>>3)*2 + 1)*GP8 + k*8 + (b & 7)] = (u & 0xFFFFFF80u) | 127u;
}

// ---- phase A: xw = x@Wx + b, split-bf16 MFMA, 128x128 tile, frags from global -
__launch_bounds__(256, 2)
__global__ void k_gemm_xw(const u16* __restrict__ xhi, const u16* __restrict__ xlo,
                          const u16* __restrict__ wthi, const u16* __restrict__ wtlo,
                          const float* __restrict__ bias, float* __restrict__ out) {
    int bid = blockIdx.x;
    int mi = bid >> 3, ni = bid & 7;
    int m0 = mi * 128, n0 = ni * 128;
    int wave = threadIdx.x >> 6, lane = threadIdx.x & 63;
    int wr = wave >> 1, wc = wave & 1;
    int lrow = lane & 15, lk8 = (lane >> 4) * 8;
    const int rowb = m0 + wr*64 + lrow;   // A row for this lane
    const int colb = n0 + wc*64 + lrow;   // B col for this lane
    f32x4 acc[4][4] = {};
    for (int kt = 0; kt < 16; ++kt) {
        int kb = kt*32 + lk8;
        short8 ah[4], al[4], bh[4], bl[4];
#pragma unroll
        for (int mt = 0; mt < 4; ++mt) {
            ah[mt] = *(const short8*)&xhi[(size_t)(rowb + mt*16)*IN_ + kb];
            al[mt] = *(const short8*)&xlo[(size_t)(rowb + mt*16)*IN_ + kb];
        }
#pragma unroll
        for (int nt = 0; nt < 4; ++nt) {
            bh[nt] = *(const short8*)&wthi[(size_t)(colb + nt*16)*IN_ + kb];
            bl[nt] = *(const short8*)&wtlo[(size_t)(colb + nt*16)*IN_ + kb];
        }
#pragma unroll
        for (int mt = 0; mt < 4; ++mt)
#pragma unroll
            for (int nt = 0; nt < 4; ++nt) {
                acc[mt][nt] = __builtin_amdgcn_mfma_f32_16x16x32_bf16(ah[mt], bh[nt], acc[mt][nt], 0,0,0);
                acc[mt][nt] = __builtin_amdgcn_mfma_f32_16x16x32_bf16(ah[mt], bl[nt], acc[mt][nt], 0,0,0);
                acc[mt][nt] = __builtin_amdgcn_mfma_f32_16x16x32_bf16(al[mt], bh[nt], acc[mt][nt], 0,0,0);
            }
    }
    // epilogue: D layout col=lane&15, row=4*(lane>>4)+reg
    int orow0 = m0 + wr*64 + 4*(lane >> 4);
#pragma unroll
    for (int nt = 0; nt < 4; ++nt) {
        int col = n0 + wc*64 + nt*16 + (lane & 15);
        float bv = bias[col];
#pragma unroll
        for (int mt = 0; mt < 4; ++mt)
#pragma unroll
            for (int r = 0; r < 4; ++r)
                out[(size_t)(orow0 + mt*16 + r)*H_ + col] = acc[mt][nt][r] + bv;
    }
}

// ---- phase A fallback (fp32 vector) if ws too small for split buffers --------
__global__ void k_gemm_f32(const float* __restrict__ A, const float* __restrict__ Bw,
                           const float* __restrict__ bias, float* __restrict__ out) {
    __shared__ float As[32][65];  // [k][m]
    __shared__ float Bs[32][65];  // [k][n]
    int n0 = blockIdx.x * 64, m0 = blockIdx.y * 64;
    int tid = threadIdx.x;
    int tr = tid >> 4, tc = tid & 15;
    float acc[4][4] = {};
    for (int kc = 0; kc < IN_; kc += 32) {
#pragma unroll
        for (int it = 0; it < 8; ++it) {
            int id = tid + 256*it;
            int k = id & 31, m = id >> 5;
            As[k][m] = A[(size_t)(m0 + m)*IN_ + kc + k];
        }
#pragma unroll
        for (int it = 0; it < 8; ++it) {
            int id = tid + 256*it;
            int n = id & 63, kk = id >> 6;
            Bs[kk][n] = Bw[(size_t)(kc + kk)*H_ + n0 + n];
        }
        __syncthreads();
#pragma unroll
        for (int kk = 0; kk < 32; ++kk) {
            float a[4], b[4];
#pragma unroll
            for (int i = 0; i < 4; ++i) a[i] = As[kk][tr*4+i];
#pragma unroll
            for (int j = 0; j < 4; ++j) b[j] = Bs[kk][tc*4+j];
#pragma unroll
            for (int i = 0; i < 4; ++i)
#pragma unroll
                for (int j = 0; j < 4; ++j) acc[i][j] += a[i]*b[j];
        }
        __syncthreads();
    }
#pragma unroll
    for (int i = 0; i < 4; ++i)
#pragma unroll
        for (int j = 0; j < 4; ++j)
            out[(size_t)(m0 + tr*4 + i)*H_ + n0 + tc*4 + j] = acc[i][j] + bias[n0 + tc*4 + j];
}

// ---- scan: 128 wgs x 512 thr, per-slice flags, own-slice-first MFMA ----------
__launch_bounds__(512, 1)
__global__ void k_scan(const float* __restrict__ wh,   // [H][H] fp32 (k-major)
                       float* __restrict__ out,        // [T][B][H] xw in / h out, + h_last tail
                       u32* __restrict__ hbufP) {      // [8 g][2 par][1024 k][8 r] tagged f32
    int bid = blockIdx.x;
    int g = bid >> 4, cw = bid & 15;      // group (8 rows), col-wg (64 cols)
    int row_g = g * 8;
    int wave = threadIdx.x >> 6, lane = threadIdx.x & 63;
    int ks = wave & 3, ch = wave >> 2;    // k-slice (256 wide), col-half (32 wide)
    int n0 = cw*64 + ch*32;
    int lrow = lane & 15, lk8 = (lane >> 4) * 8;
    const int slice  = 2*ks + ch;         // slice this wave POLLS (in its k-range)
    const int pslice = 2*ks + 1 - ch;     // partner slice (other half of k-range)

    __shared__ float hx[2][8 * 1030];         // [par][row8][k], stride 1030
    __shared__ float partial[2][8 * 8 * 33];  // [par][slot][row8][col(+pad)]
    __shared__ int flagS[2][8];               // slice-ready: holds t+1 (monotonic)

    if (threadIdx.x < 16) flagS[threadIdx.x >> 3][threadIdx.x & 7] = 0;
    __syncthreads();

    // Wh fragments ONCE: k in [ks*256,+256), cols [n0,+32)
    short8 bh[2][8], bl[2][8];
#pragma unroll
    for (int nt = 0; nt < 2; ++nt) {
        int col = n0 + nt*16 + lrow;
#pragma unroll
        for (int kt = 0; kt < 8; ++kt) {
            int kbase = ks*256 + kt*32 + lk8;
            short8 h8, l8;
#pragma unroll
            for (int j = 0; j < 8; ++j) {
                u16 hh, ll; splitbf(wh[(size_t)(kbase + j)*H_ + col], hh, ll);
                h8[j] = (short)hh; l8[j] = (short)ll;
            }
            bh[nt][kt] = h8; bl[nt][kt] = l8;
        }
    }

    // epilogue mapping (threads 0..255): ec col 0..63, er0 row-pair base
    const int ec  = threadIdx.x >> 2;
    const int er0 = (threadIdx.x & 3) * 2;
    const bool epi = (threadIdx.x < 256);
    const int ech = (ec >> 5) & 1;
    const int ecl = ec & 31;

    float xw0 = 0.f, xw1 = 0.f;
    if (epi) {
        xw0 = out[(size_t)(row_g + er0    )*H_ + cw*64 + ec];
        xw1 = out[(size_t)(row_g + er0 + 1)*H_ + cw*64 + ec];
    }

    // poll/bounce indexing: u64 #(i*64+lane) in slice: k = slice*128 + i*16 +
    // (lane>>2), rows 2*(lane&3), +1.
    const int bcol = slice*128 + (lane >> 2);
    const int brow = 2 * (lane & 3);

    // pre-loop: issue first sweep for t=0 (parity 1, written by k_h0)
    u64 raw[8];
    u32 pend = 0xFFu;
    {
        const u64* sb = (const u64*)(hbufP + (size_t)(g*2 + 1)*GP8) + slice*512;
#pragma unroll
        for (int i = 0; i < 8; ++i)
            raw[i] = __hip_atomic_load(sb + i*64 + lane, __ATOMIC_RELAXED,
                                       __HIP_MEMORY_SCOPE_AGENT);
    }

    for (int t = 0; t < T_; ++t) {
        const u32 want = 64u | (u32)((t - 1) & 63);
        const u64 want64 = ((u64)want << 32) | (u64)want;
        const int p = t & 1;
        const u64* sb = (const u64*)(hbufP + (size_t)(g*2 + ((t+1)&1))*GP8) + slice*512;

        // ---- tight validate/reload poll of OWN slice (sweep already in flight)
        for (;;) {
            u32 np = 0;
#pragma unroll
            for (int i = 0; i < 8; ++i)
                if (pend & (1u << i)) {
                    u64 bad = (raw[i] ^ want64) & 0x0000007F0000007FULL;
                    if (__any(bad != 0)) np |= 1u << i;
                }
            u32 progress = pend ^ np;
            pend = np;
            if (pend == 0) break;
            if (!progress) __builtin_amdgcn_s_sleep(1);
#pragma unroll
            for (int i = 0; i < 8; ++i)
                if (pend & (1u << i))
                    raw[i] = __hip_atomic_load(sb + i*64 + lane, __ATOMIC_RELAXED,
                                               __HIP_MEMORY_SCOPE_AGENT);
        }
        // bounce own slice to hx[p] (disjoint region per wave)
        {
            float* hxp = hx[p];
#pragma unroll
            for (int i = 0; i < 8; ++i) {
                int col = bcol + i*16;
                hxp[brow*1030 + col]     = __uint_as_float((u32)raw[i]);
                hxp[(brow+1)*1030 + col] = __uint_as_float((u32)(raw[i] >> 32));
            }
        }
        // release own-slice flag (release drains the LDS writes above)
        if (lane == 0)
            __hip_atomic_store(&flagS[p][slice], t + 1, __ATOMIC_RELEASE,
                               __HIP_MEMORY_SCOPE_WORKGROUP);
        // ensure own bounce is complete before our own fragment reads
        asm volatile("s_waitcnt lgkmcnt(0)" ::: "memory");
        __builtin_amdgcn_sched_barrier(0);

        // ---- MFMA: OWN half first (kt ch*4..+4), then partner half ----
        f32x4 acc[2][2] = {};
        const float* hxp = hx[p];
#pragma unroll
        for (int half = 0; half < 2; ++half) {
            const int kt0 = (half == 0) ? ch*4 : (1-ch)*4;
            if (half == 1) {
                while (__hip_atomic_load(&flagS[p][pslice], __ATOMIC_ACQUIRE,
                                         __HIP_MEMORY_SCOPE_WORKGROUP) < t + 1) { /*spin*/ }
            }
#pragma unroll
            for (int k4 = 0; k4 < 4; ++k4) {
                const int kt = kt0 + k4;
                const int pp = kt & 1;
                short8 ah, al;
                int cb = (lane & 7)*1030 + ks*256 + kt*32 + lk8;
#pragma unroll
                for (int j = 0; j < 8; ++j) {
                    u32 bits = __float_as_uint(hxp[cb + j]);
                    ah[j] = (short)(bits >> 16);
                    float r = __uint_as_float(bits & 0xFFFFFF80u)
                            - __uint_as_float(bits & 0xFFFF0000u);
                    al[j] = (short)(__float_as_uint(r) >> 16);
                }
#pragma unroll
                for (int nt = 0; nt < 2; ++nt) {
                    acc[nt][pp] = __builtin_amdgcn_mfma_f32_16x16x32_bf16(ah, bh[nt][kt], acc[nt][pp], 0,0,0);
                    acc[nt][pp] = __builtin_amdgcn_mfma_f32_16x16x32_bf16(ah, bl[nt][kt], acc[nt][pp], 0,0,0);
                    acc[nt][pp] = __builtin_amdgcn_mfma_f32_16x16x32_bf16(al, bh[nt][kt], acc[nt][pp], 0,0,0);
                }
            }
        }
        // K-partials (rows 0..7 in lanes 0..31): partial[p][ch*4+ks][row8][col]
        if (lane < 32) {
            int r0 = 4 * (lane >> 4);
            float* pp = partial[p] + (ch*4 + ks)*264;
#pragma unroll
            for (int nt = 0; nt < 2; ++nt) {
                int c = nt*16 + lrow;
#pragma unroll
                for (int r = 0; r < 4; ++r)
                    pp[(r0 + r)*33 + c] = acc[nt][0][r] + acc[nt][1][r];
            }
        }

        // ---- EARLY-ISSUE next step's first sweep (overlaps barrier+epilogue) ----
        if (t + 1 < T_) {
            const u64* sbn = (const u64*)(hbufP + (size_t)(g*2 + p)*GP8) + slice*512;
#pragma unroll
            for (int i = 0; i < 8; ++i)
                raw[i] = __hip_atomic_load(sbn + i*64 + lane, __ATOMIC_RELAXED,
                                           __HIP_MEMORY_SCOPE_AGENT);
            pend = 0xFFu;
        }

        __syncthreads();   // barrier2: partials complete; brackets LDS reuse
        // ---- reduce + tanh; h-store FIRST (exchange-critical), then out ----
        if (epi) {
            float s0 = xw0, s1 = xw1;
            const float* pb = partial[p];
#pragma unroll
            for (int w = 0; w < 4; ++w) {
                s0 += pb[((ech*4 + w)*8 + er0    )*33 + ecl];
                s1 += pb[((ech*4 + w)*8 + er0 + 1)*33 + ecl];
            }
            float y0 = tanhf(s0), y1 = tanhf(s1);
            const u32 tagt = 64u | (u32)(t & 63);
            u32 b0 = (__float_as_uint(y0) & 0xFFFFFF80u) | tagt;
            u32 b1 = (__float_as_uint(y1) & 0xFFFFFF80u) | tagt;
            u32* hnb = hbufP + (size_t)(g*2 + p)*GP8 + (cw*64 + ec)*8 + er0;
            (void)__hip_atomic_exchange((u64*)hnb, ((u64)b1 << 32) | (u64)b0,
                                        __ATOMIC_RELAXED, __HIP_MEMORY_SCOPE_AGENT);
            int gb0 = row_g + er0;
            out[(size_t)(t*B_ + gb0    )*H_ + cw*64 + ec] = y0;
            out[(size_t)(t*B_ + gb0 + 1)*H_ + cw*64 + ec] = y1;
            if (t == T_-1) {
                out[(size_t)TBH + (size_t)gb0*H_ + cw*64 + ec] = y0;
                out[(size_t)TBH + (size_t)(gb0+1)*H_ + cw*64 + ec] = y1;
            }
            if (t + 1 < T_) {
                xw0 = out[(size_t)((t+1)*B_ + gb0    )*H_ + cw*64 + ec];
                xw1 = out[(size_t)((t+1)*B_ + gb0 + 1)*H_ + cw*64 + ec];
            }
        }
        // Hazard audit: hx[p]/partial[p] rewrites at t+2 occur after this
        // thread's barrier2(t+1); all reads of step-t data complete before the
        // reader's barrier2(t+1) (MFMA reads before barrier2(t); epilogue
        // reads during iter t, before that thread enters iter t+1's poll and
        // reaches barrier2(t+1)). flagS is monotonic (stores t+1, increasing).
    }
}

// ---- host --------------------------------------------------------------------
extern "C" void kernel_launch(void* const* d_in, const int* in_sizes, int n_in,
                              void* d_out, int out_size, void* d_ws, size_t ws_size,
                              hipStream_t stream) {
    const float* x    = (const float*)d_in[0];
    const float* h0   = (const float*)d_in[1];
    const float* Wx   = (const float*)d_in[2];
    const float* Wh   = (const float*)d_in[3];
    const float* bias = (const float*)d_in[4];
    float* out = (float*)d_out;

    const size_t nX = (size_t)T_ * B_ * IN_;             // 16,777,216
    const size_t nWx = (size_t)IN_ * H_;                 // 524,288
    const size_t hbufB = (size_t)16 * GP8 * sizeof(u32); // 512 KB packed ping-pong
    const size_t FULL_NEED = 2*nX*2 + 2*nWx*2 + hbufB;   // ~66.5 MiB
    const size_t SAFE_NEED = hbufB;
    if (ws_size < SAFE_NEED) return;   // cannot run; fail loudly

    bool full = ws_size >= FULL_NEED;
    u16 *xhi = nullptr, *xlo = nullptr, *wthi = nullptr, *wtlo = nullptr;
    u32* hbufP;
    if (full) {
        xhi  = (u16*)d_ws;
        xlo  = xhi + nX;
        wthi = xlo + nX;
        wtlo = wthi + nWx;
        hbufP = (u32*)(wtlo + nWx);
    } else {
        hbufP = (u32*)d_ws;
    }

    // zero hbufP: tag 0 can never validate (tags are 64..127); poison 0xAA = tag 42 safe
    hipMemsetAsync(hbufP, 0, hbufB, stream);
    k_h0<<<HB/256, 256, 0, stream>>>(h0, hbufP);
    if (full) {
        k_split4<<<2048, 256, 0, stream>>>((const float4*)x, xhi, xlo, (int)(nX/4));
        k_tsplit<<<(int)(nWx/256), 256, 0, stream>>>(Wx, wthi, wtlo, IN_, H_);
        k_gemm_xw<<<2048, 256, 0, stream>>>(xhi, xlo, wthi, wtlo, bias, out);
    } else {
        k_gemm_f32<<<dim3(16, 512), 256, 0, stream>>>(x, Wx, bias, out);
    }
    k_scan<<<128, 512, 0, stream>>>(Wh, out, hbufP);
}

// Round 14
// 2390.982 us; speedup vs baseline: 2.1093x; 2.1093x over previous
//
#include <hip/hip_runtime.h>
#include <hip/hip_bf16.h>

// RNN: outs[t] = h_t = tanh(x[t]@Wx + b + h_{t-1}@Wh), T=512,B=64,IN=512,H=1024
//  - split-bf16 (hi+lo) MFMA everywhere (no fp32 MFMA on CDNA4); 3-term product
//  - phase A: xw = x@Wx+b written directly into d_out (overwritten by h_t in place)
//  - scan: persistent wgs, Wh register-resident, self-validating tagged-f32 h
//    (low 7 mantissa bits = epoch tag 64|(t&63); the poll IS the data load).
//  - R1 coherent-h: 15.5->9.5 us/step. R2 flag barrier: REGR. R3 self-valid: 6.4.
//  - R4 XCD-local w/ PLAIN stores: DEADLOCK (plain stores can sit in writeback
//    L1, invisible to sc0 polls). R5 swap-RMW: 5.9. R6 packed layout: 4.6.
//  - R7 compute-in-poll: REGR. R8 shared h-image: 4.16. R9 8-row groups +
//    early-issue + 2-barrier lockstep: 3.66 (BEST). R10/R11 courier split:
//    bug/REGR. R12 flags-instead-of-barrier1: REGR 2.5x (FETCH x10 - waves
//    desync -> failed-sweep storm). R9's lockstep sync is a local optimum.
//  - R13: R9 VERBATIM + dual-published h: producers store via L2-point
//    atomic_swap_x2 (no sc1; atomics bypass L1 - fixes R4's visibility bug)
//    into hbufF AND agent-swap into hbufP. Groups remapped g=bid&7 so a
//    group's 16 wgs share one XCD (runtime XCC_ID election). Consumers poll
//    hbufF with sc0 loads, BOUNDED 64 sweeps; timeout -> sticky fallback to
//    the R9 agent path (loads already in flight). No mode coordination
//    needed; termination guaranteed; worst case = R9 + epsilon.

#define T_ 512
#define B_ 64
#define IN_ 512
#define H_ 1024
constexpr int TBH = T_ * B_ * H_;   // 33,554,432
constexpr int HB  = B_ * H_;        // 65,536
constexpr int GP8 = 1024 * 8;       // u32s per (group,parity) packed slice (8 rows)

typedef unsigned short u16;
typedef unsigned int u32;
typedef unsigned long long u64;
typedef __attribute__((ext_vector_type(8))) short short8;   // 8 x bf16 (4 VGPRs)
typedef __attribute__((ext_vector_type(4))) float f32x4;

__device__ __forceinline__ void splitbf(float x, u16& hi, u16& lo) {
    unsigned u = __float_as_uint(x);
    hi = (u16)(u >> 16);                       // truncated bf16 hi
    float r = x - __uint_as_float(u & 0xffff0000u);
    lo = (u16)(__float_as_uint(r) >> 16);      // bf16 of residual; total rel err ~2^-16
}

// 8 contiguous-stride sc0 loads (L1-bypass, L2-read) + waitcnt, one asm block
__device__ __forceinline__ void fast_load8(const u64* sb_lane, u64 f[8]) {
    u64 r0,r1,r2,r3,r4,r5,r6,r7;
    asm volatile(
        "global_load_dwordx2 %0, %8, off sc0\n\t"
        "global_load_dwordx2 %1, %8, off offset:512 sc0\n\t"
        "global_load_dwordx2 %2, %8, off offset:1024 sc0\n\t"
        "global_load_dwordx2 %3, %8, off offset:1536 sc0\n\t"
        "global_load_dwordx2 %4, %8, off offset:2048 sc0\n\t"
        "global_load_dwordx2 %5, %8, off offset:2560 sc0\n\t"
        "global_load_dwordx2 %6, %8, off offset:3072 sc0\n\t"
        "global_load_dwordx2 %7, %8, off offset:3584 sc0\n\t"
        "s_waitcnt vmcnt(0)"
        : "=&v"(r0), "=&v"(r1), "=&v"(r2), "=&v"(r3),
          "=&v"(r4), "=&v"(r5), "=&v"(r6), "=&v"(r7)
        : "v"((u64)sb_lane) : "memory");
    f[0]=r0; f[1]=r1; f[2]=r2; f[3]=r3; f[4]=r4; f[5]=r5; f[6]=r6; f[7]=r7;
}

// L2-point atomic store (no sc1 -> executes at XCD L2; bypasses L1)
__device__ __forceinline__ void fast_store(u64* p, u64 v) {
    asm volatile("global_atomic_swap_x2 %0, %1, off" :: "v"((u64)p), "v"(v) : "memory");
}

// ---- prep kernels ------------------------------------------------------------
__global__ void k_split4(const float4* __restrict__ in, u16* __restrict__ hi,
                         u16* __restrict__ lo, int n4) {
    int i = blockIdx.x * blockDim.x + threadIdx.x;
    int stride = gridDim.x * blockDim.x;
    for (; i < n4; i += stride) {
        float4 v = in[i];
        u16 h0,h1,h2,h3,l0,l1,l2,l3;
        splitbf(v.x,h0,l0); splitbf(v.y,h1,l1); splitbf(v.z,h2,l2); splitbf(v.w,h3,l3);
        uint2 hv, lv;
        hv.x = (unsigned)h0 | ((unsigned)h1 << 16);
        hv.y = (unsigned)h2 | ((unsigned)h3 << 16);
        lv.x = (unsigned)l0 | ((unsigned)l1 << 16);
        lv.y = (unsigned)l2 | ((unsigned)l3 << 16);
        *(uint2*)&hi[4*i] = hv;
        *(uint2*)&lo[4*i] = lv;
    }
}

// src [K][N] fp32 -> dst [N][K] bf16 hi/lo (transposed for B-fragment reads)
__global__ void k_tsplit(const float* __restrict__ src, u16* __restrict__ hi,
                         u16* __restrict__ lo, int K, int N) {
    int id = blockIdx.x * 256 + threadIdx.x;
    if (id >= K * N) return;
    int k = id / N, n = id % N;
    u16 h, l; splitbf(src[id], h, l);
    hi[n*K + k] = h; lo[n*K + k] = l;
}

// h0 fp32 [B][H] -> packed tagged-f32 parity-1 of BOTH buffers (tag 127)
__global__ void k_h0(const float* __restrict__ h0, u32* __restrict__ hbufP,
                     u32* __restrict__ hbufF) {
    int id = blockIdx.x * 256 + threadIdx.x;
    if (id >= HB) return;
    int b = id >> 10, k = id & 1023;
    u32 u = __float_as_uint(h0[id]);
    u32 tv = (u & 0xFFFFFF80u) | 127u;
    size_t off = (size_t)((b>>3)*2 + 1)*GP8 + k*8 + (b & 7);
    hbufP[off] = tv;
    hbufF[off] = tv;
}

// ---- phase A: xw = x@Wx + b, split-bf16 MFMA, 128x128 tile, frags from global -
__launch_bounds__(256, 2)
__global__ void k_gemm_xw(const u16* __restrict__ xhi, const u16* __restrict__ xlo,
                          const u16* __restrict__ wthi, const u16* __restrict__ wtlo,
                          const float* __restrict__ bias, float* __restrict__ out) {
    int bid = blockIdx.x;
    int mi = bid >> 3, ni = bid & 7;
    int m0 = mi * 128, n0 = ni * 128;
    int wave = threadIdx.x >> 6, lane = threadIdx.x & 63;
    int wr = wave >> 1, wc = wave & 1;
    int lrow = lane & 15, lk8 = (lane >> 4) * 8;
    const int rowb = m0 + wr*64 + lrow;   // A row for this lane
    const int colb = n0 + wc*64 + lrow;   // B col for this lane
    f32x4 acc[4][4] = {};
    for (int kt = 0; kt < 16; ++kt) {
        int kb = kt*32 + lk8;
        short8 ah[4], al[4], bh[4], bl[4];
#pragma unroll
        for (int mt = 0; mt < 4; ++mt) {
            ah[mt] = *(const short8*)&xhi[(size_t)(rowb + mt*16)*IN_ + kb];
            al[mt] = *(const short8*)&xlo[(size_t)(rowb + mt*16)*IN_ + kb];
        }
#pragma unroll
        for (int nt = 0; nt < 4; ++nt) {
            bh[nt] = *(const short8*)&wthi[(size_t)(colb + nt*16)*IN_ + kb];
            bl[nt] = *(const short8*)&wtlo[(size_t)(colb + nt*16)*IN_ + kb];
        }
#pragma unroll
        for (int mt = 0; mt < 4; ++mt)
#pragma unroll
            for (int nt = 0; nt < 4; ++nt) {
                acc[mt][nt] = __builtin_amdgcn_mfma_f32_16x16x32_bf16(ah[mt], bh[nt], acc[mt][nt], 0,0,0);
                acc[mt][nt] = __builtin_amdgcn_mfma_f32_16x16x32_bf16(ah[mt], bl[nt], acc[mt][nt], 0,0,0);
                acc[mt][nt] = __builtin_amdgcn_mfma_f32_16x16x32_bf16(al[mt], bh[nt], acc[mt][nt], 0,0,0);
            }
    }
    // epilogue: D layout col=lane&15, row=4*(lane>>4)+reg
    int orow0 = m0 + wr*64 + 4*(lane >> 4);
#pragma unroll
    for (int nt = 0; nt < 4; ++nt) {
        int col = n0 + wc*64 + nt*16 + (lane & 15);
        float bv = bias[col];
#pragma unroll
        for (int mt = 0; mt < 4; ++mt)
#pragma unroll
            for (int r = 0; r < 4; ++r)
                out[(size_t)(orow0 + mt*16 + r)*H_ + col] = acc[mt][nt][r] + bv;
    }
}

// ---- phase A fallback (fp32 vector) if ws too small for split buffers --------
__global__ void k_gemm_f32(const float* __restrict__ A, const float* __restrict__ Bw,
                           const float* __restrict__ bias, float* __restrict__ out) {
    __shared__ float As[32][65];  // [k][m]
    __shared__ float Bs[32][65];  // [k][n]
    int n0 = blockIdx.x * 64, m0 = blockIdx.y * 64;
    int tid = threadIdx.x;
    int tr = tid >> 4, tc = tid & 15;
    float acc[4][4] = {};
    for (int kc = 0; kc < IN_; kc += 32) {
#pragma unroll
        for (int it = 0; it < 8; ++it) {
            int id = tid + 256*it;
            int k = id & 31, m = id >> 5;
            As[k][m] = A[(size_t)(m0 + m)*IN_ + kc + k];
        }
#pragma unroll
        for (int it = 0; it < 8; ++it) {
            int id = tid + 256*it;
            int n = id & 63, kk = id >> 6;
            Bs[kk][n] = Bw[(size_t)(kc + kk)*H_ + n0 + n];
        }
        __syncthreads();
#pragma unroll
        for (int kk = 0; kk < 32; ++kk) {
            float a[4], b[4];
#pragma unroll
            for (int i = 0; i < 4; ++i) a[i] = As[kk][tr*4+i];
#pragma unroll
            for (int j = 0; j < 4; ++j) b[j] = Bs[kk][tc*4+j];
#pragma unroll
            for (int i = 0; i < 4; ++i)
#pragma unroll
                for (int j = 0; j < 4; ++j) acc[i][j] += a[i]*b[j];
        }
        __syncthreads();
    }
#pragma unroll
    for (int i = 0; i < 4; ++i)
#pragma unroll
        for (int j = 0; j < 4; ++j)
            out[(size_t)(m0 + tr*4 + i)*H_ + n0 + tc*4 + j] = acc[i][j] + bias[n0 + tc*4 + j];
}

// ---- scan: R9 structure + bounded XCD-local fast poll ------------------------
__launch_bounds__(512, 1)
__global__ void k_scan(const float* __restrict__ wh,   // [H][H] fp32 (k-major)
                       float* __restrict__ out,        // [T][B][H] xw in / h out, + h_last tail
                       u32* __restrict__ hbufP,        // agent/IC buffer [8g][2par][1024k][8r]
                       u32* __restrict__ hbufF,        // L2-local buffer, same layout
                       u32* __restrict__ meta) {       // [128] XCD election
    int bid = blockIdx.x;
    int g = bid & 7, cw = bid >> 3;       // group members bid%8==g -> one XCD (round-robin)
    int row_g = g * 8;
    int wave = threadIdx.x >> 6, lane = threadIdx.x & 63;
    int ks = wave & 3, ch = wave >> 2;
    int n0 = cw*64 + ch*32;
    int lrow = lane & 15, lk8 = (lane >> 4) * 8;
    __shared__ float partial[8 * 8 * 33];    // [ch*4+ks][row8][col(+pad)]
    __shared__ float hx[8 * 1030];           // [row8][k] shared h image
    __shared__ int s_fast;

    // publish XCD id + elect (correctness never depends on the mapping)
    if (threadIdx.x == 0) {
        u32 xcd;
        asm volatile("s_getreg_b32 %0, hwreg(HW_REG_XCC_ID)" : "=s"(xcd));
        __hip_atomic_store(&meta[bid], xcd | 0x100u, __ATOMIC_RELAXED,
                           __HIP_MEMORY_SCOPE_AGENT);
    }
    // Wh fragments (overlaps peers' publishes): k in [ks*256,+256), cols [n0,+32)
    short8 bh[2][8], bl[2][8];
#pragma unroll
    for (int nt = 0; nt < 2; ++nt) {
        int col = n0 + nt*16 + lrow;
#pragma unroll
        for (int kt = 0; kt < 8; ++kt) {
            int kbase = ks*256 + kt*32 + lk8;
            short8 h8, l8;
#pragma unroll
            for (int j = 0; j < 8; ++j) {
                u16 hh, ll; splitbf(wh[(size_t)(kbase + j)*H_ + col], hh, ll);
                h8[j] = (short)hh; l8[j] = (short)ll;
            }
            bh[nt][kt] = h8; bl[nt][kt] = l8;
        }
    }
    if (wave == 0) {
        u32 v; int done;
        do {
            v = (lane < 16) ? __hip_atomic_load(&meta[g + 8*lane], __ATOMIC_RELAXED,
                                                __HIP_MEMORY_SCOPE_AGENT)
                            : 0xFFFFFFFFu;
            done = __all(lane >= 16 || v >= 0x100u);
            if (!done) __builtin_amdgcn_s_sleep(8);
        } while (!done);   // terminates: all 128 wgs are co-resident and publish
        u32 v0 = __shfl(v, 0);
        int same = __all(lane >= 16 || v == v0);
        if (lane == 0) s_fast = same;
    }
    __syncthreads();
    bool useFast = (s_fast != 0);   // sticky per-thread; wave-uniform

    // epilogue mapping (threads 0..255): ec col 0..63, er0 row-pair base
    const int ec  = threadIdx.x >> 2;
    const int er0 = (threadIdx.x & 3) * 2;
    const bool epi = (threadIdx.x < 256);
    const int ech = (ec >> 5) & 1;
    const int ecl = ec & 31;

    float xw0 = 0.f, xw1 = 0.f;
    if (epi) {
        xw0 = out[(size_t)(row_g + er0    )*H_ + cw*64 + ec];
        xw1 = out[(size_t)(row_g + er0 + 1)*H_ + cw*64 + ec];
    }

    // poll/bounce indexing (R9): wave polls k in [wave*128,+128) x 8 rows.
    const int bcol = wave*128 + (lane >> 2);
    const int brow = 2 * (lane & 3);

    // pre-loop: issue first agent sweep for t=0 (parity 1, written by k_h0)
    u64 rawA[8];
    {
        const u64* sb = (const u64*)(hbufP + (size_t)(g*2 + 1)*GP8) + wave*512;
#pragma unroll
        for (int i = 0; i < 8; ++i)
            rawA[i] = __hip_atomic_load(sb + i*64 + lane, __ATOMIC_RELAXED,
                                        __HIP_MEMORY_SCOPE_AGENT);
    }

    for (int t = 0; t < T_; ++t) {
        const u32 want = 64u | (u32)((t - 1) & 63);
        const u64 want64 = ((u64)want << 32) | (u64)want;
        const int par = t & 1;
        const u64* sbA = (const u64*)(hbufP + (size_t)(g*2 + ((t+1)&1))*GP8) + wave*512;
        const u64* sbF = (const u64*)(hbufF + (size_t)(g*2 + ((t+1)&1))*GP8) + wave*512;

        u64 val[8];
        u32 pend = 0xFFu;

        // ---- bounded XCD-local fast poll (L2 sc0 loads) ----
        if (useFast) {
            int sw = 0;
            while (pend && sw < 64) {
                u64 f[8];
                fast_load8(sbF + lane, f);
                u32 np = pend;
#pragma unroll
                for (int i = 0; i < 8; ++i)
                    if (pend & (1u << i)) {
                        u64 bad = (f[i] ^ want64) & 0x0000007F0000007FULL;
                        if (!__any(bad != 0)) { val[i] = f[i]; np &= ~(1u << i); }
                    }
                if (np == pend) __builtin_amdgcn_s_sleep(1);
                pend = np; ++sw;
            }
            if (pend) useFast = false;   // sticky fallback; agent data in flight
        }
        // ---- agent path (R9 verbatim) for whatever remains ----
        while (pend) {
            u32 np = 0;
#pragma unroll
            for (int i = 0; i < 8; ++i)
                if (pend & (1u << i)) {
                    u64 bad = (rawA[i] ^ want64) & 0x0000007F0000007FULL;
                    if (__any(bad != 0)) np |= 1u << i;
                    else val[i] = rawA[i];
                }
            u32 progress = pend ^ np;
            pend = np;
            if (pend == 0) break;
            if (!progress) __builtin_amdgcn_s_sleep(1);
#pragma unroll
            for (int i = 0; i < 8; ++i)
                if (pend & (1u << i))
                    rawA[i] = __hip_atomic_load(sbA + i*64 + lane, __ATOMIC_RELAXED,
                                                __HIP_MEMORY_SCOPE_AGENT);
        }

        // bounce to shared hx (disjoint region per wave)
#pragma unroll
        for (int i = 0; i < 8; ++i) {
            int col = bcol + i*16;
            hx[brow*1030 + col]     = __uint_as_float((u32)val[i]);
            hx[(brow+1)*1030 + col] = __uint_as_float((u32)(val[i] >> 32));
        }
        __syncthreads();   // barrier1: hx complete (all 8 slices published)

        // ---- fragments from hx (rows duplicated for M=8) + convert + MFMA ----
        f32x4 acc[2][2] = {};
#pragma unroll
        for (int kt = 0; kt < 8; ++kt) {
            int pp = kt & 1;
            short8 ah, al;
            int cb = (lrow & 7)*1030 + ks*256 + kt*32 + lk8;
#pragma unroll
            for (int j = 0; j < 8; ++j) {
                u32 bits = __float_as_uint(hx[cb + j]);
                ah[j] = (short)(bits >> 16);
                float r = __uint_as_float(bits & 0xFFFFFF80u)
                        - __uint_as_float(bits & 0xFFFF0000u);
                al[j] = (short)(__float_as_uint(r) >> 16);
            }
#pragma unroll
            for (int nt = 0; nt < 2; ++nt) {
                acc[nt][pp] = __builtin_amdgcn_mfma_f32_16x16x32_bf16(ah, bh[nt][kt], acc[nt][pp], 0,0,0);
                acc[nt][pp] = __builtin_amdgcn_mfma_f32_16x16x32_bf16(ah, bl[nt][kt], acc[nt][pp], 0,0,0);
                acc[nt][pp] = __builtin_amdgcn_mfma_f32_16x16x32_bf16(al, bh[nt][kt], acc[nt][pp], 0,0,0);
            }
        }
        // K-partials (rows 0..7 live in lanes 0..31): [ch*4+ks][row8][col]
        if (lane < 32) {
            int r0 = 4 * (lane >> 4);
#pragma unroll
            for (int nt = 0; nt < 2; ++nt) {
                int c = nt*16 + lrow;
#pragma unroll
                for (int r = 0; r < 4; ++r)
                    partial[((ch*4 + ks)*8 + r0 + r)*33 + c] = acc[nt][0][r] + acc[nt][1][r];
            }
        }

        // ---- EARLY-ISSUE next step's agent sweep (overlaps barrier+epilogue) ----
        if (t + 1 < T_) {
            const u64* sbn = (const u64*)(hbufP + (size_t)(g*2 + par)*GP8) + wave*512;
#pragma unroll
            for (int i = 0; i < 8; ++i)
                rawA[i] = __hip_atomic_load(sbn + i*64 + lane, __ATOMIC_RELAXED,
                                            __HIP_MEMORY_SCOPE_AGENT);
        }

        __syncthreads();   // barrier2
        // ---- reduce + tanh; h-stores FIRST (L2 fast, then IC), then out ----
        if (epi) {
            float s0 = xw0, s1 = xw1;
#pragma unroll
            for (int w = 0; w < 4; ++w) {
                s0 += partial[((ech*4 + w)*8 + er0    )*33 + ecl];
                s1 += partial[((ech*4 + w)*8 + er0 + 1)*33 + ecl];
            }
            float y0 = tanhf(s0), y1 = tanhf(s1);
            const u32 tagt = 64u | (u32)(t & 63);
            u32 b0 = (__float_as_uint(y0) & 0xFFFFFF80u) | tagt;
            u32 b1 = (__float_as_uint(y1) & 0xFFFFFF80u) | tagt;
            u64 v64 = ((u64)b1 << 32) | (u64)b0;
            size_t hoff = (size_t)(g*2 + par)*GP8 + (cw*64 + ec)*8 + er0;
            fast_store((u64*)&hbufF[hoff], v64);   // L2-point (same-XCD consumers)
            (void)__hip_atomic_exchange((u64*)&hbufP[hoff], v64,
                                        __ATOMIC_RELAXED, __HIP_MEMORY_SCOPE_AGENT);
            int gb0 = row_g + er0;
            out[(size_t)(t*B_ + gb0    )*H_ + cw*64 + ec] = y0;
            out[(size_t)(t*B_ + gb0 + 1)*H_ + cw*64 + ec] = y1;
            if (t == T_-1) {
                out[(size_t)TBH + (size_t)gb0*H_ + cw*64 + ec] = y0;
                out[(size_t)TBH + (size_t)(gb0+1)*H_ + cw*64 + ec] = y1;
            }
            if (t + 1 < T_) {
                xw0 = out[(size_t)((t+1)*B_ + gb0    )*H_ + cw*64 + ec];
                xw1 = out[(size_t)((t+1)*B_ + gb0 + 1)*H_ + cw*64 + ec];
            }
        }
        // LDS hazards identical to R9 (two barriers bracket hx/partial reuse).
    }
}

// ---- host --------------------------------------------------------------------
extern "C" void kernel_launch(void* const* d_in, const int* in_sizes, int n_in,
                              void* d_out, int out_size, void* d_ws, size_t ws_size,
                              hipStream_t stream) {
    const float* x    = (const float*)d_in[0];
    const float* h0   = (const float*)d_in[1];
    const float* Wx   = (const float*)d_in[2];
    const float* Wh   = (const float*)d_in[3];
    const float* bias = (const float*)d_in[4];
    float* out = (float*)d_out;

    const size_t nX = (size_t)T_ * B_ * IN_;             // 16,777,216
    const size_t nWx = (size_t)IN_ * H_;                 // 524,288
    const size_t hbufB = (size_t)16 * GP8 * sizeof(u32); // 512 KB per buffer
    const size_t metaB = 128 * sizeof(u32);
    const size_t scanB = 2*hbufB + metaB;                // ~1 MB
    const size_t FULL_NEED = 2*nX*2 + 2*nWx*2 + scanB;   // ~67 MiB
    const size_t SAFE_NEED = scanB;
    if (ws_size < SAFE_NEED) return;   // cannot run; fail loudly

    bool full = ws_size >= FULL_NEED;
    u16 *xhi = nullptr, *xlo = nullptr, *wthi = nullptr, *wtlo = nullptr;
    u32* hbufP;
    if (full) {
        xhi  = (u16*)d_ws;
        xlo  = xhi + nX;
        wthi = xlo + nX;
        wtlo = wthi + nWx;
        hbufP = (u32*)(wtlo + nWx);
    } else {
        hbufP = (u32*)d_ws;
    }
    u32* hbufF = hbufP + 16*GP8;
    u32* meta  = hbufF + 16*GP8;

    // zero both h buffers (tags 64..127 can't alias 0 / 0xAA poison) + meta
    hipMemsetAsync(hbufP, 0, scanB, stream);
    k_h0<<<HB/256, 256, 0, stream>>>(h0, hbufP, hbufF);
    if (full) {
        k_split4<<<2048, 256, 0, stream>>>((const float4*)x, xhi, xlo, (int)(nX/4));
        k_tsplit<<<(int)(nWx/256), 256, 0, stream>>>(Wx, wthi, wtlo, IN_, H_);
        k_gemm_xw<<<2048, 256, 0, stream>>>(xhi, xlo, wthi, wtlo, bias, out);
    } else {
        k_gemm_f32<<<dim3(16, 512), 256, 0, stream>>>(x, Wx, bias, out);
    }
    k_scan<<<128, 512, 0, stream>>>(Wh, out, hbufP, hbufF, meta);
}

// Round 15
// 2113.792 us; speedup vs baseline: 2.3860x; 1.1311x over previous
//
#include <hip/hip_runtime.h>
#include <hip/hip_bf16.h>

// RNN: outs[t] = h_t = tanh(x[t]@Wx + b + h_{t-1}@Wh), T=512,B=64,IN=512,H=1024
//  - split-bf16 (hi+lo) MFMA everywhere (no fp32 MFMA on CDNA4); 3-term product
//  - phase A: xw = x@Wx+b written directly into d_out (overwritten by h_t in place)
//  - scan: persistent wgs, Wh register-resident, self-validating tagged-f32 h
//    (low 7 mantissa bits = epoch tag 64|(t&63); the poll IS the data load).
//  - R1 coherent-h: 15.5->9.5 us/step. R2 flag barrier: REGR. R3 self-valid: 6.4.
//  - R4 XCD-local plain stores: DEADLOCK. R5 swap-RMW: 5.9. R6 packed: 4.6.
//  - R7 compute-in-poll: REGR. R8 shared h-image: 4.16. R9 8-row groups +
//    early-issue + 2-barrier lockstep: 3.66 (BEST). R10/R11 courier: bug/REGR.
//  - R12 flags-for-barrier1: REGR 2.5x (wave desync -> failed-sweep storm).
//  - R13 bounded XCD-local L2 fast path: WORKED (FETCH 595->167MB) but SLOWER
//    (2207 vs 1872): early-issue overlap already hides most of the IC detect
//    leg, and the L2 read-storm contends with producer swaps on the same
//    lines. Conclusion: R9's {agent-scope exchange + early-issued sweep +
//    2-barrier lockstep} is the measured optimum across 14 variants.
//  - R14: exact revert to R9 (best known: scan 1872 us, total 2110 us).

#define T_ 512
#define B_ 64
#define IN_ 512
#define H_ 1024
constexpr int TBH = T_ * B_ * H_;   // 33,554,432
constexpr int HB  = B_ * H_;        // 65,536
constexpr int GP8 = 1024 * 8;       // u32s per (group,parity) packed slice (8 rows)

typedef unsigned short u16;
typedef unsigned int u32;
typedef unsigned long long u64;
typedef __attribute__((ext_vector_type(8))) short short8;   // 8 x bf16 (4 VGPRs)
typedef __attribute__((ext_vector_type(4))) float f32x4;

__device__ __forceinline__ void splitbf(float x, u16& hi, u16& lo) {
    unsigned u = __float_as_uint(x);
    hi = (u16)(u >> 16);                       // truncated bf16 hi
    float r = x - __uint_as_float(u & 0xffff0000u);
    lo = (u16)(__float_as_uint(r) >> 16);      // bf16 of residual; total rel err ~2^-16
}

// ---- prep kernels ------------------------------------------------------------
__global__ void k_split4(const float4* __restrict__ in, u16* __restrict__ hi,
                         u16* __restrict__ lo, int n4) {
    int i = blockIdx.x * blockDim.x + threadIdx.x;
    int stride = gridDim.x * blockDim.x;
    for (; i < n4; i += stride) {
        float4 v = in[i];
        u16 h0,h1,h2,h3,l0,l1,l2,l3;
        splitbf(v.x,h0,l0); splitbf(v.y,h1,l1); splitbf(v.z,h2,l2); splitbf(v.w,h3,l3);
        uint2 hv, lv;
        hv.x = (unsigned)h0 | ((unsigned)h1 << 16);
        hv.y = (unsigned)h2 | ((unsigned)h3 << 16);
        lv.x = (unsigned)l0 | ((unsigned)l1 << 16);
        lv.y = (unsigned)l2 | ((unsigned)l3 << 16);
        *(uint2*)&hi[4*i] = hv;
        *(uint2*)&lo[4*i] = lv;
    }
}

// src [K][N] fp32 -> dst [N][K] bf16 hi/lo (transposed for B-fragment reads)
__global__ void k_tsplit(const float* __restrict__ src, u16* __restrict__ hi,
                         u16* __restrict__ lo, int K, int N) {
    int id = blockIdx.x * 256 + threadIdx.x;
    if (id >= K * N) return;
    int k = id / N, n = id % N;
    u16 h, l; splitbf(src[id], h, l);
    hi[n*K + k] = h; lo[n*K + k] = l;
}

// h0 fp32 [B][H] -> packed tagged-f32 parity-1 (read at t=0, expects tag 127)
__global__ void k_h0(const float* __restrict__ h0, u32* __restrict__ hbufP) {
    int id = blockIdx.x * 256 + threadIdx.x;
    if (id >= HB) return;
    int b = id >> 10, k = id & 1023;
    u32 u = __float_as_uint(h0[id]);
    hbufP[(size_t)((b>>3)*2 + 1)*GP8 + k*8 + (b & 7)] = (u & 0xFFFFFF80u) | 127u;
}

// ---- phase A: xw = x@Wx + b, split-bf16 MFMA, 128x128 tile, frags from global -
__launch_bounds__(256, 2)
__global__ void k_gemm_xw(const u16* __restrict__ xhi, const u16* __restrict__ xlo,
                          const u16* __restrict__ wthi, const u16* __restrict__ wtlo,
                          const float* __restrict__ bias, float* __restrict__ out) {
    int bid = blockIdx.x;
    int mi = bid >> 3, ni = bid & 7;
    int m0 = mi * 128, n0 = ni * 128;
    int wave = threadIdx.x >> 6, lane = threadIdx.x & 63;
    int wr = wave >> 1, wc = wave & 1;
    int lrow = lane & 15, lk8 = (lane >> 4) * 8;
    const int rowb = m0 + wr*64 + lrow;   // A row for this lane
    const int colb = n0 + wc*64 + lrow;   // B col for this lane
    f32x4 acc[4][4] = {};
    for (int kt = 0; kt < 16; ++kt) {
        int kb = kt*32 + lk8;
        short8 ah[4], al[4], bh[4], bl[4];
#pragma unroll
        for (int mt = 0; mt < 4; ++mt) {
            ah[mt] = *(const short8*)&xhi[(size_t)(rowb + mt*16)*IN_ + kb];
            al[mt] = *(const short8*)&xlo[(size_t)(rowb + mt*16)*IN_ + kb];
        }
#pragma unroll
        for (int nt = 0; nt < 4; ++nt) {
            bh[nt] = *(const short8*)&wthi[(size_t)(colb + nt*16)*IN_ + kb];
            bl[nt] = *(const short8*)&wtlo[(size_t)(colb + nt*16)*IN_ + kb];
        }
#pragma unroll
        for (int mt = 0; mt < 4; ++mt)
#pragma unroll
            for (int nt = 0; nt < 4; ++nt) {
                acc[mt][nt] = __builtin_amdgcn_mfma_f32_16x16x32_bf16(ah[mt], bh[nt], acc[mt][nt], 0,0,0);
                acc[mt][nt] = __builtin_amdgcn_mfma_f32_16x16x32_bf16(ah[mt], bl[nt], acc[mt][nt], 0,0,0);
                acc[mt][nt] = __builtin_amdgcn_mfma_f32_16x16x32_bf16(al[mt], bh[nt], acc[mt][nt], 0,0,0);
            }
    }
    // epilogue: D layout col=lane&15, row=4*(lane>>4)+reg
    int orow0 = m0 + wr*64 + 4*(lane >> 4);
#pragma unroll
    for (int nt = 0; nt < 4; ++nt) {
        int col = n0 + wc*64 + nt*16 + (lane & 15);
        float bv = bias[col];
#pragma unroll
        for (int mt = 0; mt < 4; ++mt)
#pragma unroll
            for (int r = 0; r < 4; ++r)
                out[(size_t)(orow0 + mt*16 + r)*H_ + col] = acc[mt][nt][r] + bv;
    }
}

// ---- phase A fallback (fp32 vector) if ws too small for split buffers --------
__global__ void k_gemm_f32(const float* __restrict__ A, const float* __restrict__ Bw,
                           const float* __restrict__ bias, float* __restrict__ out) {
    __shared__ float As[32][65];  // [k][m]
    __shared__ float Bs[32][65];  // [k][n]
    int n0 = blockIdx.x * 64, m0 = blockIdx.y * 64;
    int tid = threadIdx.x;
    int tr = tid >> 4, tc = tid & 15;
    float acc[4][4] = {};
    for (int kc = 0; kc < IN_; kc += 32) {
#pragma unroll
        for (int it = 0; it < 8; ++it) {
            int id = tid + 256*it;
            int k = id & 31, m = id >> 5;
            As[k][m] = A[(size_t)(m0 + m)*IN_ + kc + k];
        }
#pragma unroll
        for (int it = 0; it < 8; ++it) {
            int id = tid + 256*it;
            int n = id & 63, kk = id >> 6;
            Bs[kk][n] = Bw[(size_t)(kc + kk)*H_ + n0 + n];
        }
        __syncthreads();
#pragma unroll
        for (int kk = 0; kk < 32; ++kk) {
            float a[4], b[4];
#pragma unroll
            for (int i = 0; i < 4; ++i) a[i] = As[kk][tr*4+i];
#pragma unroll
            for (int j = 0; j < 4; ++j) b[j] = Bs[kk][tc*4+j];
#pragma unroll
            for (int i = 0; i < 4; ++i)
#pragma unroll
                for (int j = 0; j < 4; ++j) acc[i][j] += a[i]*b[j];
        }
        __syncthreads();
    }
#pragma unroll
    for (int i = 0; i < 4; ++i)
#pragma unroll
        for (int j = 0; j < 4; ++j)
            out[(size_t)(m0 + tr*4 + i)*H_ + n0 + tc*4 + j] = acc[i][j] + bias[n0 + tc*4 + j];
}

// ---- scan: 128 wgs x 512 thr, 8-row groups, early-issued poll sweeps ---------
__launch_bounds__(512, 1)
__global__ void k_scan(const float* __restrict__ wh,   // [H][H] fp32 (k-major)
                       float* __restrict__ out,        // [T][B][H] xw in / h out, + h_last tail
                       u32* __restrict__ hbufP) {      // [8 g][2 par][1024 k][8 r] tagged f32
    int bid = blockIdx.x;
    int g = bid >> 4, cw = bid & 15;      // group (8 rows), col-wg (64 cols)
    int row_g = g * 8;
    int wave = threadIdx.x >> 6, lane = threadIdx.x & 63;
    int ks = wave & 3, ch = wave >> 2;    // k-slice (256 wide), col-half (32 wide)
    int n0 = cw*64 + ch*32;               // this wave's first col
    int lrow = lane & 15, lk8 = (lane >> 4) * 8;
    __shared__ float partial[8 * 8 * 33];    // [ch*4+ks][row8][col(+pad)]
    __shared__ float hx[8 * 1030];           // [row8][k] shared h image, stride 1030

    // Load Wh fragments ONCE: this wave covers k in [ks*256,+256), cols [n0,+32)
    short8 bh[2][8], bl[2][8];
#pragma unroll
    for (int nt = 0; nt < 2; ++nt) {
        int col = n0 + nt*16 + lrow;
#pragma unroll
        for (int kt = 0; kt < 8; ++kt) {
            int kbase = ks*256 + kt*32 + lk8;
            short8 h8, l8;
#pragma unroll
            for (int j = 0; j < 8; ++j) {
                u16 hh, ll; splitbf(wh[(size_t)(kbase + j)*H_ + col], hh, ll);
                h8[j] = (short)hh; l8[j] = (short)ll;
            }
            bh[nt][kt] = h8; bl[nt][kt] = l8;
        }
    }

    // epilogue mapping: threads 0..255: ec = col 0..63, er0 = row-pair base
    const int ec  = threadIdx.x >> 2;        // 0..127 (only <64 used via tid<256)
    const int er0 = (threadIdx.x & 3) * 2;   // 0,2,4,6
    const bool epi = (threadIdx.x < 256);
    const int ech = (ec >> 5) & 1;           // col-half for partial reads
    const int ecl = ec & 31;

    // prefetch xw for t=0
    float xw0 = 0.f, xw1 = 0.f;
    if (epi) {
        xw0 = out[(size_t)(row_g + er0    )*H_ + cw*64 + ec];
        xw1 = out[(size_t)(row_g + er0 + 1)*H_ + cw*64 + ec];
    }

    // poll/bounce indexing: wave polls k in [wave*128,+128) x 8 rows = 4KB.
    // u64 #(i*64+lane): k = wave*128 + i*16 + (lane>>2), rows 2*(lane&3), +1.
    const int bcol = wave*128 + (lane >> 2);
    const int brow = 2 * (lane & 3);

    // ---- pre-loop: issue first sweep for t=0 (parity 1, written by k_h0) ----
    u64 raw[8];
    u32 pend = 0xFFu;
    {
        const u64* sb = (const u64*)(hbufP + (size_t)(g*2 + 1)*GP8) + wave*512;
#pragma unroll
        for (int i = 0; i < 8; ++i)
            raw[i] = __hip_atomic_load(sb + i*64 + lane, __ATOMIC_RELAXED,
                                       __HIP_MEMORY_SCOPE_AGENT);
    }

    for (int t = 0; t < T_; ++t) {
        const u32 want = 64u | (u32)((t - 1) & 63);
        const u64 want64 = ((u64)want << 32) | (u64)want;
        const int par = t & 1;
        const u64* sb = (const u64*)(hbufP + (size_t)(g*2 + ((t+1)&1))*GP8) + wave*512;

        // ---- tight validate/reload poll (first sweep already in flight) ----
        for (;;) {
            u32 np = 0;
#pragma unroll
            for (int i = 0; i < 8; ++i)
                if (pend & (1u << i)) {
                    u64 bad = (raw[i] ^ want64) & 0x0000007F0000007FULL;
                    if (__any(bad != 0)) np |= 1u << i;
                }
            u32 progress = pend ^ np;
            pend = np;
            if (pend == 0) break;
            if (!progress) __builtin_amdgcn_s_sleep(1);
#pragma unroll
            for (int i = 0; i < 8; ++i)
                if (pend & (1u << i))
                    raw[i] = __hip_atomic_load(sb + i*64 + lane, __ATOMIC_RELAXED,
                                               __HIP_MEMORY_SCOPE_AGENT);
        }
        // bounce to shared hx (disjoint region per wave)
#pragma unroll
        for (int i = 0; i < 8; ++i) {
            int col = bcol + i*16;
            hx[brow*1030 + col]     = __uint_as_float((u32)raw[i]);
            hx[(brow+1)*1030 + col] = __uint_as_float((u32)(raw[i] >> 32));
        }
        __syncthreads();   // hx complete (all 8 slices published)

        // ---- fragments from hx (rows duplicated for M=8) + convert + MFMA ----
        f32x4 acc[2][2] = {};
#pragma unroll
        for (int kt = 0; kt < 8; ++kt) {
            int p = kt & 1;
            short8 ah, al;
            int cb = (lrow & 7)*1030 + ks*256 + kt*32 + lk8;
#pragma unroll
            for (int j = 0; j < 8; ++j) {
                u32 bits = __float_as_uint(hx[cb + j]);
                ah[j] = (short)(bits >> 16);
                float r = __uint_as_float(bits & 0xFFFFFF80u)
                        - __uint_as_float(bits & 0xFFFF0000u);
                al[j] = (short)(__float_as_uint(r) >> 16);
            }
#pragma unroll
            for (int nt = 0; nt < 2; ++nt) {
                acc[nt][p] = __builtin_amdgcn_mfma_f32_16x16x32_bf16(ah, bh[nt][kt], acc[nt][p], 0,0,0);
                acc[nt][p] = __builtin_amdgcn_mfma_f32_16x16x32_bf16(ah, bl[nt][kt], acc[nt][p], 0,0,0);
                acc[nt][p] = __builtin_amdgcn_mfma_f32_16x16x32_bf16(al, bh[nt][kt], acc[nt][p], 0,0,0);
            }
        }
        // K-partials (rows 0..7 live in lanes 0..31): [ch*4+ks][row8][col]
        if (lane < 32) {
            int r0 = 4 * (lane >> 4);
#pragma unroll
            for (int nt = 0; nt < 2; ++nt) {
                int c = nt*16 + lrow;
#pragma unroll
                for (int r = 0; r < 4; ++r)
                    partial[((ch*4 + ks)*8 + r0 + r)*33 + c] = acc[nt][0][r] + acc[nt][1][r];
            }
        }

        // ---- EARLY-ISSUE next step's first sweep (overlaps barrier+epilogue) ----
        if (t + 1 < T_) {
            const u64* sbn = (const u64*)(hbufP + (size_t)(g*2 + par)*GP8) + wave*512;
#pragma unroll
            for (int i = 0; i < 8; ++i)
                raw[i] = __hip_atomic_load(sbn + i*64 + lane, __ATOMIC_RELAXED,
                                           __HIP_MEMORY_SCOPE_AGENT);
            pend = 0xFFu;
        }

        __syncthreads();
        // ---- reduce + tanh; h-store FIRST (exchange-critical), then out ----
        if (epi) {
            float s0 = xw0, s1 = xw1;
#pragma unroll
            for (int w = 0; w < 4; ++w) {
                s0 += partial[((ech*4 + w)*8 + er0    )*33 + ecl];
                s1 += partial[((ech*4 + w)*8 + er0 + 1)*33 + ecl];
            }
            float y0 = tanhf(s0), y1 = tanhf(s1);
            const u32 tagt = 64u | (u32)(t & 63);
            u32 b0 = (__float_as_uint(y0) & 0xFFFFFF80u) | tagt;
            u32 b1 = (__float_as_uint(y1) & 0xFFFFFF80u) | tagt;
            // packed [col][row-pair] -> one contiguous u64 swap (RMW at coherence pt)
            u32* hnb = hbufP + (size_t)(g*2 + par)*GP8 + (cw*64 + ec)*8 + er0;
            (void)__hip_atomic_exchange((u64*)hnb, ((u64)b1 << 32) | (u64)b0,
                                        __ATOMIC_RELAXED, __HIP_MEMORY_SCOPE_AGENT);
            int gb0 = row_g + er0;
            out[(size_t)(t*B_ + gb0    )*H_ + cw*64 + ec] = y0;
            out[(size_t)(t*B_ + gb0 + 1)*H_ + cw*64 + ec] = y1;
            if (t == T_-1) {
                out[(size_t)TBH + (size_t)gb0*H_ + cw*64 + ec] = y0;
                out[(size_t)TBH + (size_t)(gb0+1)*H_ + cw*64 + ec] = y1;
            }
            // prefetch next xw (latency hides under next step's h polling)
            if (t + 1 < T_) {
                xw0 = out[(size_t)((t+1)*B_ + gb0    )*H_ + cw*64 + ec];
                xw1 = out[(size_t)((t+1)*B_ + gb0 + 1)*H_ + cw*64 + ec];
            }
        }
        // LDS hazards: hx/partial writes of t+1 happen after barrier1(t+1);
        // all reads of t's data complete before this thread leaves its barriers.
    }
}

// ---- host --------------------------------------------------------------------
extern "C" void kernel_launch(void* const* d_in, const int* in_sizes, int n_in,
                              void* d_out, int out_size, void* d_ws, size_t ws_size,
                              hipStream_t stream) {
    const float* x    = (const float*)d_in[0];
    const float* h0   = (const float*)d_in[1];
    const float* Wx   = (const float*)d_in[2];
    const float* Wh   = (const float*)d_in[3];
    const float* bias = (const float*)d_in[4];
    float* out = (float*)d_out;

    const size_t nX = (size_t)T_ * B_ * IN_;             // 16,777,216
    const size_t nWx = (size_t)IN_ * H_;                 // 524,288
    const size_t hbufB = (size_t)16 * GP8 * sizeof(u32); // 512 KB packed ping-pong
    const size_t FULL_NEED = 2*nX*2 + 2*nWx*2 + hbufB;   // ~66.5 MiB
    const size_t SAFE_NEED = hbufB;
    if (ws_size < SAFE_NEED) return;   // cannot run; fail loudly

    bool full = ws_size >= FULL_NEED;
    u16 *xhi = nullptr, *xlo = nullptr, *wthi = nullptr, *wtlo = nullptr;
    u32* hbufP;
    if (full) {
        xhi  = (u16*)d_ws;
        xlo  = xhi + nX;
        wthi = xlo + nX;
        wtlo = wthi + nWx;
        hbufP = (u32*)(wtlo + nWx);
    } else {
        hbufP = (u32*)d_ws;
    }

    // zero hbufP: tag 0 can never validate (tags are 64..127); poison 0xAA = tag 42 safe
    hipMemsetAsync(hbufP, 0, hbufB, stream);
    k_h0<<<HB/256, 256, 0, stream>>>(h0, hbufP);
    if (full) {
        k_split4<<<2048, 256, 0, stream>>>((const float4*)x, xhi, xlo, (int)(nX/4));
        k_tsplit<<<(int)(nWx/256), 256, 0, stream>>>(Wx, wthi, wtlo, IN_, H_);
        k_gemm_xw<<<2048, 256, 0, stream>>>(xhi, xlo, wthi, wtlo, bias, out);
    } else {
        k_gemm_f32<<<dim3(16, 512), 256, 0, stream>>>(x, Wx, bias, out);
    }
    k_scan<<<128, 512, 0, stream>>>(Wh, out, hbufP);
}